// Round 6
// baseline (137.284 us; speedup 1.0000x reference)
//
#include <hip/hip_runtime.h>

#define NH 16

typedef __bf16 bf16x8 __attribute__((ext_vector_type(8)));
typedef unsigned short u16x8 __attribute__((ext_vector_type(8)));
typedef float f32x4 __attribute__((ext_vector_type(4)));
typedef unsigned short u16;

__device__ __forceinline__ u16 f2bu(float f) {
    unsigned int u = __builtin_bit_cast(unsigned int, f);
    u = (u + 0x7FFFu + ((u >> 16) & 1u)) >> 16;
    return (u16)u;
}
__device__ __forceinline__ bf16x8 ld_bf8(const u16* p) {
    return __builtin_bit_cast(bf16x8, *(const u16x8*)p);
}
__device__ __forceinline__ void gl_lds16(const void* g, void* l) {
    __builtin_amdgcn_global_load_lds((const __attribute__((address_space(1))) void*)g,
                                     (__attribute__((address_space(3))) void*)l, 16, 0, 0);
}

__device__ __forceinline__ int rel_bucket(int delta) {
    int n = -delta;
    int ret = (n < 0) ? 16 : 0;
    int na = n < 0 ? -n : n;
    int b;
    if (na < 8) b = na;
    else if (na < 12) b = 8;
    else if (na < 16) b = 9;
    else if (na < 23) b = 10;
    else if (na < 32) b = 11;
    else if (na < 46) b = 12;
    else if (na < 64) b = 13;
    else if (na < 91) b = 14;
    else b = 15;
    return b + ret;
}

#define L2E 1.4426950408889634f

// ---------------- prep: x cast + 4x weight transpose ----------------
__global__ void prep_all(const float* __restrict__ x, u16* __restrict__ xb, int n,
                         const float* __restrict__ Wq, const float* __restrict__ Wk,
                         const float* __restrict__ Wv, const float* __restrict__ Wo,
                         u16* __restrict__ Wt, u16* __restrict__ Wot, int cb) {
    __shared__ float tile[32][33];
    int b = blockIdx.x, tid = threadIdx.x;
    if (b < cb) {
        int i = (b * 256 + tid) * 4;
        if (i >= n) return;
        float4 v = *(const float4*)&x[i];
        u16 o0 = f2bu(v.x), o1 = f2bu(v.y), o2 = f2bu(v.z), o3 = f2bu(v.w);
        xb[i] = o0; xb[i+1] = o1; xb[i+2] = o2; xb[i+3] = o3;
    } else {
        int t = b - cb;
        int z = t >> 10; t &= 1023;
        const float* src = z == 0 ? Wq : z == 1 ? Wk : z == 2 ? Wv : Wo;
        u16* dst = z < 3 ? Wt + (size_t)z * 1024 * 1024 : Wot;
        int r0 = (t >> 5) * 32, c0 = (t & 31) * 32;
        int tx = tid & 31, ty = tid >> 5;
        #pragma unroll
        for (int i = 0; i < 32; i += 8)
            tile[ty + i][tx] = src[(size_t)(r0 + ty + i) * 1024 + c0 + tx];
        __syncthreads();
        #pragma unroll
        for (int i = 0; i < 32; i += 8)
            dst[(size_t)(c0 + ty + i) * 1024 + r0 + tx] = f2bu(tile[tx][ty + i]);
    }
}

// ---------------- GEMM (m97 single-buffer structure, rectangle XCD-L2 tiling) ----------------
template<int MODE, int BM, int XR, int XC>
__global__ __launch_bounds__(256)
void gemm_bt(const u16* __restrict__ A, const u16* __restrict__ Bt,
             int N, int K, int T,
             float* __restrict__ Cf, u16* __restrict__ qkb, u16* __restrict__ vtb) {
    constexpr int MI = BM / 32;
    constexpr int STG = (BM + 128) * 64;     // u16
    constexpr int LDSN = (MODE == 1 && 128 * 136 > STG) ? 128 * 136 : STG;
    __shared__ __attribute__((aligned(16))) u16 lds[LDSN];
    const int tid = threadIdx.x;
    const int l = tid & 63, wv = tid >> 6;
    const int l16 = l & 15, lg = l >> 4;
    const int lrow = l >> 3, lslot = l & 7;
    const int wm = (wv >> 1) * (BM / 2), wn = (wv & 1) * 64;

    int bmi, bni;
    {
        int gx = gridDim.x, gy = gridDim.y;
        int lin = blockIdx.y * gx + blockIdx.x;
        int nrx = gx / XR, nrc = gy / XC;
        if (gx % XR == 0 && gy % XC == 0 && nrx * nrc == 8) {
            int xcd = lin & 7, loc = lin >> 3;
            int rr = xcd / nrc, rc = xcd % nrc;
            bmi = rr * XR + (loc % XR);
            bni = rc * XC + (loc / XR);
        } else { bmi = blockIdx.x; bni = blockIdx.y; }
    }
    const int bm = bmi * BM, bn = bni * 128;

    f32x4 acc[MI][4];
    #pragma unroll
    for (int i = 0; i < MI; i++)
        #pragma unroll
        for (int j = 0; j < 4; j++)
            #pragma unroll
            for (int r = 0; r < 4; r++) acc[i][j][r] = 0.f;

    u16* As_ = lds;
    u16* Bs_ = lds + BM * 64;
    for (int k0 = 0; k0 < K; k0 += 64) {
        __syncthreads();
        #pragma unroll
        for (int c = 0; c < MI; ++c) {
            int chunk = c * 4 + wv;
            int row = chunk * 8 + lrow;
            int gs = lslot ^ (row & 7);
            gl_lds16(&A[(size_t)(bm + row) * K + k0 + gs * 8], &As_[chunk * 512]);
        }
        #pragma unroll
        for (int c = 0; c < 4; ++c) {
            int chunk = c * 4 + wv;
            int row = chunk * 8 + lrow;
            int gs = lslot ^ (row & 7);
            gl_lds16(&Bt[(size_t)(bn + row) * K + k0 + gs * 8], &Bs_[chunk * 512]);
        }
        __syncthreads();
        #pragma unroll
        for (int kk = 0; kk < 2; ++kk) {
            bf16x8 af[MI], bfv[4];
            #pragma unroll
            for (int i = 0; i < MI; i++) {
                int row = wm + i * 16 + l16;
                af[i] = ld_bf8(&As_[row * 64 + (((kk * 4 + lg) ^ (row & 7)) * 8)]);
            }
            #pragma unroll
            for (int j = 0; j < 4; j++) {
                int row = wn + j * 16 + l16;
                bfv[j] = ld_bf8(&Bs_[row * 64 + (((kk * 4 + lg) ^ (row & 7)) * 8)]);
            }
            #pragma unroll
            for (int i = 0; i < MI; i++)
                #pragma unroll
                for (int j = 0; j < 4; j++)
                    acc[i][j] = __builtin_amdgcn_mfma_f32_16x16x32_bf16(af[i], bfv[j], acc[i][j], 0, 0, 0);
        }
    }

    if (MODE == 0) {
        #pragma unroll
        for (int i = 0; i < MI; i++)
            #pragma unroll
            for (int j = 0; j < 4; j++) {
                int col = bn + wn + j * 16 + l16;
                #pragma unroll
                for (int r = 0; r < 4; r++) {
                    int row = bm + wm + i * 16 + lg * 4 + r;
                    Cf[(size_t)row * N + col] = acc[i][j][r];
                }
            }
    } else if (bn < 2048) {
        #pragma unroll
        for (int i = 0; i < MI; i++)
            #pragma unroll
            for (int j = 0; j < 4; j++) {
                int col = bn + wn + j * 16 + l16;
                #pragma unroll
                for (int r = 0; r < 4; r++) {
                    int row = bm + wm + i * 16 + lg * 4 + r;
                    qkb[(size_t)row * 2048 + col] = f2bu(acc[i][j][r]);
                }
            }
    } else {
        __syncthreads();                        // all waves done reading lds
        #pragma unroll
        for (int i = 0; i < MI; i++)
            #pragma unroll
            for (int j = 0; j < 4; j++) {
                int cl = wn + j * 16 + l16;
                #pragma unroll
                for (int r = 0; r < 4; r++)
                    lds[cl * 136 + wm + i * 16 + lg * 4 + r] = f2bu(acc[i][j][r]);
            }
        __syncthreads();
        int cl = tid >> 1, hf = tid & 1;
        size_t gb = (size_t)(bn - 2048 + cl) * T + bm + hf * 64;
        #pragma unroll
        for (int k2 = 0; k2 < 8; ++k2) {
            int4 v4 = *(const int4*)&lds[cl * 136 + hf * 64 + k2 * 8];
            *(int4*)&vtb[gb + k2 * 8] = v4;
        }
    }
}

// ---------------- attention: QBLK=64, 4 waves, dbuf K/V, self-contained bias/meta ----------------
__global__ __launch_bounds__(256)
void attn_kernel(const u16* __restrict__ qkb, const u16* __restrict__ vtb,
                 const float* __restrict__ tbl, const int* __restrict__ q_lens, int nseq,
                 u16* __restrict__ attnb, int T) {
    __shared__ __attribute__((aligned(16))) u16 KV[2][2][4096];
    __shared__ __attribute__((aligned(16))) u16 Ps[4][16][72];
    __shared__ float biasLds[2112];
    const int tid = threadIdx.x;
    const int l = tid & 63, wv = tid >> 6;
    const int l16 = l & 15, lg = l >> 4;
    const int lrow = l >> 3, lslot = l & 7;

    // XCD swizzle: each XCD owns 2 heads' full q-range (K/V L2-resident)
    int nbk = gridDim.x * gridDim.y;
    int lin = blockIdx.y * gridDim.x + blockIdx.x;
    int lin2 = (nbk & 7) ? lin : (lin & 7) * (nbk >> 3) + (lin >> 3);
    const int h = lin2 / gridDim.x;
    const int q0 = (lin2 % gridDim.x) * 64;

    int cums[9]; cums[0] = 0;
    #pragma unroll
    for (int i = 0; i < 8; ++i) cums[i + 1] = cums[i] + (i < nseq ? q_lens[i] : 0);
    auto seq_of = [&](int t) -> int {
        int s = -1;
        #pragma unroll
        for (int i = 0; i < 8; ++i)
            if (t >= cums[i] && t < cums[i + 1]) s = i;
        return s;
    };
    const int s0 = seq_of(q0), s1 = seq_of(q0 + 63);
    const bool uni = (s0 == s1) && (s0 >= 0);
    const int kvA = uni ? cums[s0] : 0;
    const int kvB = uni ? cums[s0 + 1] : T;
    const int len = kvB - kvA;

    // biasLds[(tk - kvA) + 63 - (tq - q0)]
    for (int t = tid; t < len + 64; t += 256)
        biasLds[t] = tbl[rel_bucket(kvA - q0 - 63 + t) * NH + h] * L2E;

    bf16x8 qf[2];
    {
        int tq = q0 + wv * 16 + l16;
        const u16* qp = qkb + (size_t)tq * 2048 + h * 64 + lg * 8;
        qf[0] = ld_bf8(qp); qf[1] = ld_bf8(qp + 32);
    }
    int tqr[4], sqr[4];
    #pragma unroll
    for (int r = 0; r < 4; r++) {
        tqr[r] = q0 + wv * 16 + lg * 4 + r;
        sqr[r] = uni ? s0 : seq_of(tqr[r]);
    }

    const u16* kg = qkb + 1024 + h * 64;
    const u16* vg = vtb + (size_t)(h * 64) * T;
    auto stage = [&](int base, int bi) {
        #pragma unroll
        for (int c = 0; c < 2; ++c) {
            int chunk = c * 4 + wv;
            int row = chunk * 8 + lrow;
            int gs = lslot ^ (row & 7);
            int tk = base + row; if (tk > T - 1) tk = T - 1;
            gl_lds16(kg + (size_t)tk * 2048 + gs * 8, &KV[bi][0][chunk * 512]);
            gl_lds16(vg + (size_t)row * T + base + gs * 8, &KV[bi][1][chunk * 512]);
        }
    };

    float psum[4] = {0.f, 0.f, 0.f, 0.f};
    f32x4 o[4];
    #pragma unroll
    for (int d = 0; d < 4; d++)
        #pragma unroll
        for (int r = 0; r < 4; r++) o[d][r] = 0.f;

    stage(kvA, 0);
    __syncthreads();
    int cur = 0;
    for (int base = kvA; base < kvB; base += 64) {
        if (base + 64 < kvB) stage(base + 64, cur ^ 1);
        const u16* Kb = KV[cur][0];
        const u16* Vb = KV[cur][1];

        f32x4 s[4];
        #pragma unroll
        for (int kt = 0; kt < 4; kt++)
            #pragma unroll
            for (int r = 0; r < 4; r++) s[kt][r] = 0.f;
        #pragma unroll
        for (int kk = 0; kk < 2; kk++)
            #pragma unroll
            for (int kt = 0; kt < 4; kt++) {
                int rw = kt * 16 + l16;
                bf16x8 kf = ld_bf8(Kb + rw * 64 + (((kk * 4 + lg) ^ (rw & 7)) * 8));
                s[kt] = __builtin_amdgcn_mfma_f32_16x16x32_bf16(qf[kk], kf, s[kt], 0, 0, 0);
            }

        const int cbi = (base - kvA) + 63 + l16 - wv * 16 - lg * 4;
        if (uni && base + 64 <= kvB) {
            #pragma unroll
            for (int r = 0; r < 4; r++) {
                const float* bp = &biasLds[cbi - r];
                #pragma unroll
                for (int kt = 0; kt < 4; kt++) {
                    float p = __builtin_amdgcn_exp2f(__builtin_fmaf(s[kt][r], L2E, bp[kt * 16]));
                    psum[r] += p;
                    Ps[wv][lg * 4 + r][kt * 16 + l16] = f2bu(p);
                }
            }
        } else {
            int skt[4];
            #pragma unroll
            for (int kt = 0; kt < 4; kt++) {
                int tk = base + kt * 16 + l16;
                skt[kt] = (tk < T) ? (uni ? s0 : seq_of(tk)) : -2;
            }
            #pragma unroll
            for (int r = 0; r < 4; r++) {
                const float* bp = &biasLds[cbi - r];
                #pragma unroll
                for (int kt = 0; kt < 4; kt++) {
                    float p = __builtin_amdgcn_exp2f(__builtin_fmaf(s[kt][r], L2E, bp[kt * 16]));
                    if (uni) {
                        int tk = base + kt * 16 + l16;
                        if (tk >= kvB) p = 0.f;
                    } else {
                        bool ok = (skt[kt] >= 0) && (skt[kt] == sqr[r]);
                        p = (sqr[r] < 0) ? 1.f : (ok ? p : 0.f);
                    }
                    psum[r] += p;
                    Ps[wv][lg * 4 + r][kt * 16 + l16] = f2bu(p);
                }
            }
        }
        // PV: same-wave P round-trip, no barrier
        bf16x8 pf0 = ld_bf8(&Ps[wv][l16][lg * 8]);
        bf16x8 pf1 = ld_bf8(&Ps[wv][l16][32 + lg * 8]);
        #pragma unroll
        for (int kk = 0; kk < 2; kk++) {
            bf16x8 pf = kk ? pf1 : pf0;
            #pragma unroll
            for (int dt = 0; dt < 4; dt++) {
                int rw = dt * 16 + l16;
                bf16x8 vf = ld_bf8(Vb + rw * 64 + (((kk * 4 + lg) ^ (rw & 7)) * 8));
                o[dt] = __builtin_amdgcn_mfma_f32_16x16x32_bf16(pf, vf, o[dt], 0, 0, 0);
            }
        }
        __syncthreads();
        cur ^= 1;
    }

    float lsum[4];
    #pragma unroll
    for (int r = 0; r < 4; r++) {
        float v = psum[r];
        #pragma unroll
        for (int m = 1; m < 16; m <<= 1) v += __shfl_xor(v, m, 64);
        lsum[r] = v;
    }
    #pragma unroll
    for (int dt = 0; dt < 4; dt++)
        #pragma unroll
        for (int r = 0; r < 4; r++)
            attnb[(size_t)tqr[r] * 1024 + h * 64 + dt * 16 + l16] = f2bu(o[dt][r] / lsum[r]);
}

// ---------------- launch ----------------
extern "C" void kernel_launch(void* const* d_in, const int* in_sizes, int n_in,
                              void* d_out, int out_size, void* d_ws, size_t ws_size,
                              hipStream_t stream) {
    const float* x   = (const float*)d_in[0];
    const float* Wq  = (const float*)d_in[1];
    const float* Wk  = (const float*)d_in[2];
    const float* Wv  = (const float*)d_in[3];
    const float* Wo  = (const float*)d_in[4];
    const float* tbl = (const float*)d_in[5];
    const int* q_lens = (const int*)d_in[6];
    const int T = in_sizes[0] / 1024;
    const int nseq = in_sizes[6];

    char* ws = (char*)d_ws;
    auto alloc = [&](size_t bytes) { char* p = ws; ws += (bytes + 255) & ~(size_t)255; return p; };
    u16*   xb    = (u16*)alloc((size_t)T * 1024 * 2);
    u16*   Wt    = (u16*)alloc((size_t)3072 * 1024 * 2);
    u16*   Wot   = (u16*)alloc((size_t)1024 * 1024 * 2);
    u16*   qkb   = (u16*)alloc((size_t)T * 2048 * 2);
    u16*   vtb   = (u16*)alloc((size_t)1024 * T * 2);
    u16*   attnb = (u16*)alloc((size_t)T * 1024 * 2);

    int cb = (T * 1024 / 4 + 255) / 256;
    prep_all<<<dim3(cb + 4096), dim3(256), 0, stream>>>(
        x, xb, T * 1024, Wq, Wk, Wv, Wo, Wt, Wot, cb);

    gemm_bt<1, 128, 8, 6><<<dim3(T / 128, 3072 / 128), dim3(256), 0, stream>>>(
        xb, Wt, 3072, 1024, T, nullptr, qkb, vtb);
    attn_kernel<<<dim3(T / 64, NH), dim3(256), 0, stream>>>(
        qkb, vtb, tbl, q_lens, nseq, attnb, T);
    gemm_bt<0, 64, 8, 4><<<dim3(T / 64, 1024 / 128), dim3(256), 0, stream>>>(
        attnb, Wot, 1024, 1024, T, (float*)d_out, nullptr, nullptr);
}

// Round 7
// 127.674 us; speedup vs baseline: 1.0753x; 1.0753x over previous
//
#include <hip/hip_runtime.h>

#define NH 16

typedef __bf16 bf16x8 __attribute__((ext_vector_type(8)));
typedef unsigned short u16x8 __attribute__((ext_vector_type(8)));
typedef float f32x4 __attribute__((ext_vector_type(4)));
typedef unsigned short u16;

__device__ __forceinline__ u16 f2bu(float f) {
    unsigned int u = __builtin_bit_cast(unsigned int, f);
    u = (u + 0x7FFFu + ((u >> 16) & 1u)) >> 16;
    return (u16)u;
}
__device__ __forceinline__ bf16x8 ld_bf8(const u16* p) {
    return __builtin_bit_cast(bf16x8, *(const u16x8*)p);
}
__device__ __forceinline__ void gl_lds16(const void* g, void* l) {
    __builtin_amdgcn_global_load_lds((const __attribute__((address_space(1))) void*)g,
                                     (__attribute__((address_space(3))) void*)l, 16, 0, 0);
}

__device__ __forceinline__ int rel_bucket(int delta) {
    int n = -delta;
    int ret = (n < 0) ? 16 : 0;
    int na = n < 0 ? -n : n;
    int b;
    if (na < 8) b = na;
    else if (na < 12) b = 8;
    else if (na < 16) b = 9;
    else if (na < 23) b = 10;
    else if (na < 32) b = 11;
    else if (na < 46) b = 12;
    else if (na < 64) b = 13;
    else if (na < 91) b = 14;
    else b = 15;
    return b + ret;
}

#define L2E 1.4426950408889634f

// ---------------- prep: x cast + 4x weight transpose ----------------
__global__ void prep_all(const float* __restrict__ x, u16* __restrict__ xb, int n,
                         const float* __restrict__ Wq, const float* __restrict__ Wk,
                         const float* __restrict__ Wv, const float* __restrict__ Wo,
                         u16* __restrict__ Wt, u16* __restrict__ Wot, int cb) {
    __shared__ float tile[32][33];
    int b = blockIdx.x, tid = threadIdx.x;
    if (b < cb) {
        int i = (b * 256 + tid) * 4;
        if (i >= n) return;
        float4 v = *(const float4*)&x[i];
        u16 o0 = f2bu(v.x), o1 = f2bu(v.y), o2 = f2bu(v.z), o3 = f2bu(v.w);
        xb[i] = o0; xb[i+1] = o1; xb[i+2] = o2; xb[i+3] = o3;
    } else {
        int t = b - cb;
        int z = t >> 10; t &= 1023;
        const float* src = z == 0 ? Wq : z == 1 ? Wk : z == 2 ? Wv : Wo;
        u16* dst = z < 3 ? Wt + (size_t)z * 1024 * 1024 : Wot;
        int r0 = (t >> 5) * 32, c0 = (t & 31) * 32;
        int tx = tid & 31, ty = tid >> 5;
        #pragma unroll
        for (int i = 0; i < 32; i += 8)
            tile[ty + i][tx] = src[(size_t)(r0 + ty + i) * 1024 + c0 + tx];
        __syncthreads();
        #pragma unroll
        for (int i = 0; i < 32; i += 8)
            dst[(size_t)(c0 + ty + i) * 1024 + r0 + tx] = f2bu(tile[tx][ty + i]);
    }
}

// ---------------- GEMM (2-phase dbuf, rectangle XCD-L2 tiling) — R5 config ----------------
template<int MODE, int BM, int XR, int XC>
__global__ __launch_bounds__(256)
void gemm_bt(const u16* __restrict__ A, const u16* __restrict__ Bt,
             int N, int K, int T,
             float* __restrict__ Cf, u16* __restrict__ qkb, u16* __restrict__ vtb) {
    constexpr int MI = BM / 32;
    constexpr int STG = (BM + 128) * 64;
    constexpr int LDSN = (MODE == 1 && 128 * 136 > 2 * STG) ? 128 * 136 : 2 * STG;
    __shared__ __attribute__((aligned(16))) u16 lds[LDSN];
    const int tid = threadIdx.x;
    const int l = tid & 63, wv = tid >> 6;
    const int l16 = l & 15, lg = l >> 4;
    const int lrow = l >> 3, lslot = l & 7;
    const int wm = (wv >> 1) * (BM / 2), wn = (wv & 1) * 64;

    int bmi, bni;
    {
        int gx = gridDim.x, gy = gridDim.y;
        int lin = blockIdx.y * gx + blockIdx.x;
        int nrx = gx / XR, nrc = gy / XC;
        if (gx % XR == 0 && gy % XC == 0 && nrx * nrc == 8) {
            int xcd = lin & 7, loc = lin >> 3;
            int rr = xcd / nrc, rc = xcd % nrc;
            bmi = rr * XR + (loc % XR);
            bni = rc * XC + (loc / XR);
        } else { bmi = blockIdx.x; bni = blockIdx.y; }
    }
    const int bm = bmi * BM, bn = bni * 128;

    f32x4 acc[MI][4];
    #pragma unroll
    for (int i = 0; i < MI; i++)
        #pragma unroll
        for (int j = 0; j < 4; j++)
            #pragma unroll
            for (int r = 0; r < 4; r++) acc[i][j][r] = 0.f;

    auto stage = [&](int k0, int bi) {
        u16* As_ = lds + bi * STG;
        u16* Bs_ = As_ + BM * 64;
        #pragma unroll
        for (int c = 0; c < MI; ++c) {
            int chunk = c * 4 + wv;
            int row = chunk * 8 + lrow;
            int gs = lslot ^ (row & 7);
            gl_lds16(&A[(size_t)(bm + row) * K + k0 + gs * 8], &As_[chunk * 512]);
        }
        #pragma unroll
        for (int c = 0; c < 4; ++c) {
            int chunk = c * 4 + wv;
            int row = chunk * 8 + lrow;
            int gs = lslot ^ (row & 7);
            gl_lds16(&Bt[(size_t)(bn + row) * K + k0 + gs * 8], &Bs_[chunk * 512]);
        }
    };

    stage(0, 0);
    __syncthreads();
    int cur = 0;
    for (int k0 = 0; k0 < K; k0 += 64) {
        if (k0 + 64 < K) stage(k0 + 64, cur ^ 1);
        const u16* As = lds + cur * STG;
        const u16* Bs = As + BM * 64;
        #pragma unroll
        for (int kk = 0; kk < 2; ++kk) {
            bf16x8 af[MI], bfv[4];
            #pragma unroll
            for (int i = 0; i < MI; i++) {
                int row = wm + i * 16 + l16;
                af[i] = ld_bf8(&As[row * 64 + (((kk * 4 + lg) ^ (row & 7)) * 8)]);
            }
            #pragma unroll
            for (int j = 0; j < 4; j++) {
                int row = wn + j * 16 + l16;
                bfv[j] = ld_bf8(&Bs[row * 64 + (((kk * 4 + lg) ^ (row & 7)) * 8)]);
            }
            #pragma unroll
            for (int i = 0; i < MI; i++)
                #pragma unroll
                for (int j = 0; j < 4; j++)
                    acc[i][j] = __builtin_amdgcn_mfma_f32_16x16x32_bf16(af[i], bfv[j], acc[i][j], 0, 0, 0);
        }
        __syncthreads();
        cur ^= 1;
    }

    if (MODE == 0) {
        #pragma unroll
        for (int i = 0; i < MI; i++)
            #pragma unroll
            for (int j = 0; j < 4; j++) {
                int col = bn + wn + j * 16 + l16;
                #pragma unroll
                for (int r = 0; r < 4; r++) {
                    int row = bm + wm + i * 16 + lg * 4 + r;
                    Cf[(size_t)row * N + col] = acc[i][j][r];
                }
            }
    } else if (bn < 2048) {
        #pragma unroll
        for (int i = 0; i < MI; i++)
            #pragma unroll
            for (int j = 0; j < 4; j++) {
                int col = bn + wn + j * 16 + l16;
                #pragma unroll
                for (int r = 0; r < 4; r++) {
                    int row = bm + wm + i * 16 + lg * 4 + r;
                    qkb[(size_t)row * 2048 + col] = f2bu(acc[i][j][r]);
                }
            }
    } else {
        #pragma unroll
        for (int i = 0; i < MI; i++)
            #pragma unroll
            for (int j = 0; j < 4; j++) {
                int cl = wn + j * 16 + l16;
                #pragma unroll
                for (int r = 0; r < 4; r++)
                    lds[cl * 136 + wm + i * 16 + lg * 4 + r] = f2bu(acc[i][j][r]);
            }
        __syncthreads();
        int cl = tid >> 1, hf = tid & 1;
        size_t gb = (size_t)(bn - 2048 + cl) * T + bm + hf * 64;
        #pragma unroll
        for (int k2 = 0; k2 < 8; ++k2) {
            int4 v4 = *(const int4*)&lds[cl * 136 + hf * 64 + k2 * 8];
            *(int4*)&vtb[gb + k2 * 8] = v4;
        }
    }
}

// ---------------- attention: QBLK=128, 8 waves, T14 reg-staged K/V dbuf ----------------
__global__ __launch_bounds__(512)
void attn_kernel(const u16* __restrict__ qkb, const u16* __restrict__ vtb,
                 const float* __restrict__ tbl, const int* __restrict__ q_lens, int nseq,
                 u16* __restrict__ attnb, int T) {
    __shared__ __attribute__((aligned(16))) u16 KV[2][2][4096];
    __shared__ __attribute__((aligned(16))) u16 Ps[8][16][72];
    __shared__ float biasLds[2304];
    const int tid = threadIdx.x;
    const int l = tid & 63, wv = tid >> 6;
    const int l16 = l & 15, lg = l >> 4;
    const int lrow = l >> 3, lslot = l & 7;

    int nbk = gridDim.x * gridDim.y;
    int lin = blockIdx.y * gridDim.x + blockIdx.x;
    int lin2 = (nbk & 7) ? lin : (lin & 7) * (nbk >> 3) + (lin >> 3);
    const int h = lin2 / gridDim.x;
    const int q0 = (lin2 % gridDim.x) * 128;

    int cums[9]; cums[0] = 0;
    #pragma unroll
    for (int i = 0; i < 8; ++i) cums[i + 1] = cums[i] + (i < nseq ? q_lens[i] : 0);
    auto seq_of = [&](int t) -> int {
        int s = -1;
        #pragma unroll
        for (int i = 0; i < 8; ++i)
            if (t >= cums[i] && t < cums[i + 1]) s = i;
        return s;
    };
    const int s0 = seq_of(q0), s1 = seq_of(q0 + 127);
    const bool uni = (s0 == s1) && (s0 >= 0);
    const int kvA = uni ? cums[s0] : 0;
    const int kvB = uni ? cums[s0 + 1] : T;
    const int len = kvB - kvA;

    for (int t = tid; t < len + 128; t += 512)
        biasLds[t] = tbl[rel_bucket(kvA - q0 - 127 + t) * NH + h] * L2E;

    bf16x8 qf[2];
    {
        int tq = q0 + wv * 16 + l16;
        const u16* qp = qkb + (size_t)tq * 2048 + h * 64 + lg * 8;
        qf[0] = ld_bf8(qp); qf[1] = ld_bf8(qp + 32);
    }
    int tqr[4], sqr[4];
    #pragma unroll
    for (int r = 0; r < 4; r++) {
        tqr[r] = q0 + wv * 16 + lg * 4 + r;
        sqr[r] = uni ? s0 : seq_of(tqr[r]);
    }

    const u16* kg = qkb + 1024 + h * 64;
    const u16* vg = vtb + (size_t)(h * 64) * T;
    const int srow = wv * 8 + lrow;                 // this lane's staged row (0..63)
    const int swz = (lslot ^ (srow & 7)) * 8;       // write-side XOR swizzle

    // T14 reg-staging: issue-early (to regs), write-late (to LDS after compute)
    auto ldKV = [&](int base, int4& kr, int4& vr) {
        int tk = base + srow; if (tk > T - 1) tk = T - 1;
        kr = *(const int4*)(kg + (size_t)tk * 2048 + lslot * 8);
        vr = *(const int4*)(vg + (size_t)srow * T + base + lslot * 8);
    };
    auto stKV = [&](int bi, const int4& kr, const int4& vr) {
        *(int4*)&KV[bi][0][srow * 64 + swz] = kr;
        *(int4*)&KV[bi][1][srow * 64 + swz] = vr;
    };

    float psum[4] = {0.f, 0.f, 0.f, 0.f};
    f32x4 o[4];
    #pragma unroll
    for (int d = 0; d < 4; d++)
        #pragma unroll
        for (int r = 0; r < 4; r++) o[d][r] = 0.f;

    int4 kr, vr;
    ldKV(kvA, kr, vr);
    stKV(0, kr, vr);
    if (kvA + 64 < kvB) ldKV(kvA + 64, kr, vr);     // tile1 in flight during tile0 compute
    __syncthreads();
    int cur = 0;
    for (int base = kvA; base < kvB; base += 64) {
        const u16* Kb = KV[cur][0];
        const u16* Vb = KV[cur][1];

        f32x4 s[4];
        #pragma unroll
        for (int kt = 0; kt < 4; kt++)
            #pragma unroll
            for (int r = 0; r < 4; r++) s[kt][r] = 0.f;
        #pragma unroll
        for (int kk = 0; kk < 2; kk++)
            #pragma unroll
            for (int kt = 0; kt < 4; kt++) {
                int rw = kt * 16 + l16;
                bf16x8 kf = ld_bf8(Kb + rw * 64 + (((kk * 4 + lg) ^ (rw & 7)) * 8));
                s[kt] = __builtin_amdgcn_mfma_f32_16x16x32_bf16(qf[kk], kf, s[kt], 0, 0, 0);
            }

        const int cbi = (base - kvA) + 127 + l16 - wv * 16 - lg * 4;
        if (uni && base + 64 <= kvB) {
            #pragma unroll
            for (int r = 0; r < 4; r++) {
                const float* bp = &biasLds[cbi - r];
                #pragma unroll
                for (int kt = 0; kt < 4; kt++) {
                    float p = __builtin_amdgcn_exp2f(__builtin_fmaf(s[kt][r], L2E, bp[kt * 16]));
                    psum[r] += p;
                    Ps[wv][lg * 4 + r][kt * 16 + l16] = f2bu(p);
                }
            }
        } else {
            int skt[4];
            #pragma unroll
            for (int kt = 0; kt < 4; kt++) {
                int tk = base + kt * 16 + l16;
                skt[kt] = (tk < T) ? (uni ? s0 : seq_of(tk)) : -2;
            }
            #pragma unroll
            for (int r = 0; r < 4; r++) {
                const float* bp = &biasLds[cbi - r];
                #pragma unroll
                for (int kt = 0; kt < 4; kt++) {
                    float p = __builtin_amdgcn_exp2f(__builtin_fmaf(s[kt][r], L2E, bp[kt * 16]));
                    if (uni) {
                        int tk = base + kt * 16 + l16;
                        if (tk >= kvB) p = 0.f;
                    } else {
                        bool ok = (skt[kt] >= 0) && (skt[kt] == sqr[r]);
                        p = (sqr[r] < 0) ? 1.f : (ok ? p : 0.f);
                    }
                    psum[r] += p;
                    Ps[wv][lg * 4 + r][kt * 16 + l16] = f2bu(p);
                }
            }
        }
        // PV: same-wave P round-trip, no barrier
        bf16x8 pf0 = ld_bf8(&Ps[wv][l16][lg * 8]);
        bf16x8 pf1 = ld_bf8(&Ps[wv][l16][32 + lg * 8]);
        #pragma unroll
        for (int kk = 0; kk < 2; kk++) {
            bf16x8 pf = kk ? pf1 : pf0;
            #pragma unroll
            for (int dt = 0; dt < 4; dt++) {
                int rw = dt * 16 + l16;
                bf16x8 vf = ld_bf8(Vb + rw * 64 + (((kk * 4 + lg) ^ (rw & 7)) * 8));
                o[dt] = __builtin_amdgcn_mfma_f32_16x16x32_bf16(pf, vf, o[dt], 0, 0, 0);
            }
        }
        // write-late: staged regs -> other buffer; issue next-next load
        if (base + 64 < kvB) {
            stKV(cur ^ 1, kr, vr);
            if (base + 128 < kvB) ldKV(base + 128, kr, vr);
        }
        __syncthreads();
        cur ^= 1;
    }

    float lsum[4];
    #pragma unroll
    for (int r = 0; r < 4; r++) {
        float v = psum[r];
        #pragma unroll
        for (int m = 1; m < 16; m <<= 1) v += __shfl_xor(v, m, 64);
        lsum[r] = v;
    }
    #pragma unroll
    for (int dt = 0; dt < 4; dt++)
        #pragma unroll
        for (int r = 0; r < 4; r++)
            attnb[(size_t)tqr[r] * 1024 + h * 64 + dt * 16 + l16] = f2bu(o[dt][r] / lsum[r]);
}

// ---------------- launch ----------------
extern "C" void kernel_launch(void* const* d_in, const int* in_sizes, int n_in,
                              void* d_out, int out_size, void* d_ws, size_t ws_size,
                              hipStream_t stream) {
    const float* x   = (const float*)d_in[0];
    const float* Wq  = (const float*)d_in[1];
    const float* Wk  = (const float*)d_in[2];
    const float* Wv  = (const float*)d_in[3];
    const float* Wo  = (const float*)d_in[4];
    const float* tbl = (const float*)d_in[5];
    const int* q_lens = (const int*)d_in[6];
    const int T = in_sizes[0] / 1024;
    const int nseq = in_sizes[6];

    char* ws = (char*)d_ws;
    auto alloc = [&](size_t bytes) { char* p = ws; ws += (bytes + 255) & ~(size_t)255; return p; };
    u16*   xb    = (u16*)alloc((size_t)T * 1024 * 2);
    u16*   Wt    = (u16*)alloc((size_t)3072 * 1024 * 2);
    u16*   Wot   = (u16*)alloc((size_t)1024 * 1024 * 2);
    u16*   qkb   = (u16*)alloc((size_t)T * 2048 * 2);
    u16*   vtb   = (u16*)alloc((size_t)1024 * T * 2);
    u16*   attnb = (u16*)alloc((size_t)T * 1024 * 2);

    int cb = (T * 1024 / 4 + 255) / 256;
    prep_all<<<dim3(cb + 4096), dim3(256), 0, stream>>>(
        x, xb, T * 1024, Wq, Wk, Wv, Wo, Wt, Wot, cb);

    gemm_bt<1, 128, 8, 6><<<dim3(T / 128, 3072 / 128), dim3(256), 0, stream>>>(
        xb, Wt, 3072, 1024, T, nullptr, qkb, vtb);
    attn_kernel<<<dim3(T / 128, NH), dim3(512), 0, stream>>>(
        qkb, vtb, tbl, q_lens, nseq, attnb, T);
    gemm_bt<0, 64, 8, 4><<<dim3(T / 64, 1024 / 128), dim3(256), 0, stream>>>(
        attnb, Wot, 1024, 1024, T, (float*)d_out, nullptr, nullptr);
}